// Round 1
// 6126.616 us; speedup vs baseline: 1.8921x; 1.8921x over previous
//
#include <hip/hip_runtime.h>
#include <hip/hip_bf16.h>

// RSSM scan, restructured (R2):
//  - gates GEMM split-K + rebalanced: RZ (K=3072) -> 2x1536, HN (K=2048) -> 2x1024,
//    448 blocks (>=2 resident/CU) instead of 256x1; partials summed in gate_k
//  - postW1 GEMM split-K x4 -> 128 blocks of 8 K-iters, f32 partials; elu+bias+epart
//    deferred into the fused head kernel
//  - za/reset producer fused into head kernel (head of step t builds X_rz for t+1);
//    za_hreset_k only bootstraps t=0. Per-step chain: gates -> gate -> postw1 -> head.
//  - Uacc / Upri alias the Grz region (sequential stream ordering makes this safe);
//    total ws = 155.5 MB (< previous 160.8 MB known-good footprint)
// R1 fix kept: reset marshalled as int32.

using namespace std;

typedef __attribute__((ext_vector_type(4))) float  f32x4;
typedef __attribute__((ext_vector_type(8))) short  short8;
typedef __attribute__((ext_vector_type(4))) short  short4v;

#define T_STEPS 64
#define BATCH   512

__device__ __forceinline__ float b2f(short s) {
    union { unsigned u; float f; } v; v.u = ((unsigned)(unsigned short)s) << 16; return v.f;
}
__device__ __forceinline__ short f2b(float f) {  // RNE
    unsigned u = __float_as_uint(f);
    unsigned r = u + 0x7FFF + ((u >> 16) & 1);
    return (short)(r >> 16);
}
__device__ __forceinline__ void async_copy16(const void* g, void* l) {
    __builtin_amdgcn_global_load_lds(
        (__attribute__((address_space(1))) void*)(void*)(size_t)(const char*)g,
        (__attribute__((address_space(3))) void*)l, 16, 0, 0);
}
__device__ __forceinline__ float sigmoidf_(float x) { return 1.f / (1.f + __expf(-x)); }
__device__ __forceinline__ float eluf_(float x) { return x > 0.f ? x : expm1f(x); }
__device__ __forceinline__ float softplusf_(float x) {
    return fmaxf(x, 0.f) + log1pf(__expf(-fabsf(x)));
}

// ---------------------------------------------------------------------------
// GEMM core: C_tile(128x128) at (row0,col0) = A(MxK) * B^T, B stored N-major (NxK) bf16.
// 256 threads, 4 waves in 2x2, wave tile 64x64, BK=64.
// ---------------------------------------------------------------------------
template <bool AF32>
__device__ __forceinline__ void gemm_core(const void* Aptr, const short* B, int K,
                                          int lda, int ldb, int row0, int col0,
                                          short* lA, short* lB, f32x4 acc[4][4]) {
    const int tid = threadIdx.x, lane = tid & 63, wave = tid >> 6;
    const int wm = wave & 1, wn = wave >> 1;
#pragma unroll
    for (int mt = 0; mt < 4; ++mt)
#pragma unroll
        for (int nt = 0; nt < 4; ++nt) acc[mt][nt] = f32x4{0.f, 0.f, 0.f, 0.f};

    const short* Ab = (const short*)Aptr;
    const float* Af = (const float*)Aptr;
    const int arow = wm * 64 + (lane & 15);
    const int brow = wn * 64 + (lane & 15);
    const int kq   = (lane >> 4) << 3;

    for (int k0 = 0; k0 < K; k0 += 64) {
        __syncthreads();
        if (AF32) {
#pragma unroll
            for (int i = 0; i < 8; ++i) {
                int idx = i * 256 + tid;
                int r = idx >> 4, c = (idx & 15) << 2;
                const float4 v = *(const float4*)(Af + (size_t)(row0 + r) * lda + k0 + c);
                short4v s; s.x = f2b(v.x); s.y = f2b(v.y); s.z = f2b(v.z); s.w = f2b(v.w);
                *(short4v*)&lA[r * 64 + c] = s;
            }
        } else {
#pragma unroll
            for (int i = 0; i < 4; ++i) {
                int r = i * 32 + wave * 8 + (lane >> 3);
                int c = (lane & 7) << 3;
                async_copy16(Ab + (size_t)(row0 + r) * lda + k0 + c, &lA[(i * 32 + wave * 8) * 64]);
            }
        }
#pragma unroll
        for (int i = 0; i < 4; ++i) {
            int r = i * 32 + wave * 8 + (lane >> 3);
            int c = (lane & 7) << 3;
            async_copy16(B + (size_t)(col0 + r) * ldb + k0 + c, &lB[(i * 32 + wave * 8) * 64]);
        }
        __syncthreads();
#pragma unroll
        for (int kk = 0; kk < 64; kk += 32) {
            short8 af[4], bf_[4];
#pragma unroll
            for (int mt = 0; mt < 4; ++mt) af[mt] = *(short8*)&lA[(arow + mt * 16) * 64 + kk + kq];
#pragma unroll
            for (int nt = 0; nt < 4; ++nt) bf_[nt] = *(short8*)&lB[(brow + nt * 16) * 64 + kk + kq];
#pragma unroll
            for (int mt = 0; mt < 4; ++mt)
#pragma unroll
                for (int nt = 0; nt < 4; ++nt)
                    acc[mt][nt] = __builtin_amdgcn_mfma_f32_16x16x32_bf16(af[mt], bf_[nt], acc[mt][nt], 0, 0, 0);
        }
    }
}

struct Epi {
    const float* bias;   // nullable, [col]
    const short* add;    // nullable bf16 addend matrix
    int add_ld;
    float* Cf; int ldcf; // nullable f32 out
    short* Cb; int ldcb; // nullable bf16 out
    int elu;
};

template <bool AF32>
__global__ __launch_bounds__(256, 2) void gemm_k(const void* A, const short* B, int K,
                                                 int lda, int ldb, int mtiles, Epi ep) {
    __shared__ short lA[128 * 64];
    __shared__ short lB[128 * 64];
    const int bm = blockIdx.x % mtiles, bn = blockIdx.x / mtiles;
    f32x4 acc[4][4];
    gemm_core<AF32>(A, B, K, lda, ldb, bm * 128, bn * 128, lA, lB, acc);
    const int lane = threadIdx.x & 63, wave = threadIdx.x >> 6;
    const int wm = wave & 1, wn = wave >> 1;
    const int rbase = bm * 128 + wm * 64 + ((lane >> 4) << 2);
    const int cbase = bn * 128 + wn * 64 + (lane & 15);
#pragma unroll
    for (int mt = 0; mt < 4; ++mt)
#pragma unroll
        for (int nt = 0; nt < 4; ++nt)
#pragma unroll
            for (int r = 0; r < 4; ++r) {
                const int row = rbase + mt * 16 + r;
                const int col = cbase + nt * 16;
                float x = acc[mt][nt][r];
                if (ep.bias) x += ep.bias[col];
                if (ep.add)  x += b2f(ep.add[(size_t)row * ep.add_ld + col]);
                if (ep.elu)  x = eluf_(x);
                if (ep.Cf) ep.Cf[(size_t)row * ep.ldcf + col] = x;
                if (ep.Cb) ep.Cb[(size_t)row * ep.ldcb + col] = f2b(x);
            }
}

// Gate GEMMs, split-K rebalanced, one dispatch of 448 blocks:
//  bid 0..255   : RZ  [za|h](512x3072) @ Wrz^T(4096x3072), split-K x2 (K=1536 each)
//  bid 256..319 : IN  za(512x1024) @ Win^T(2048x1024)
//  bid 320..447 : HN  h(512x2048) @ Whn^T(2048x2048), split-K x2 (K=1024 each)
__global__ __launch_bounds__(256, 2) void gates_k(const short* Xrz, const short* Wrz,
                                                  const short* Win, const short* Whn,
                                                  float* Grz, float* Gin, float* Ghn) {
    __shared__ short lA[128 * 64];
    __shared__ short lB[128 * 64];
    const int bid = blockIdx.x;
    const short *A, *B; float* C; int K, lda, ldb, ldc, bm, bn;
    if (bid < 256) {
        const int ks = bid >> 7, t2 = bid & 127;
        A = Xrz + ks * 1536; B = Wrz + ks * 1536; C = Grz + (size_t)ks * 512 * 4096;
        K = 1536; lda = 3072; ldb = 3072; ldc = 4096; bm = t2 & 3; bn = t2 >> 2;
    } else if (bid < 320) {
        const int t2 = bid - 256;
        A = Xrz; B = Win; C = Gin;
        K = 1024; lda = 3072; ldb = 1024; ldc = 2048; bm = t2 & 3; bn = t2 >> 2;
    } else {
        const int t2 = bid - 320, ks = t2 >> 6, t3 = t2 & 63;
        A = Xrz + 1024 + ks * 1024; B = Whn + ks * 1024; C = Ghn + (size_t)ks * 512 * 2048;
        K = 1024; lda = 3072; ldb = 2048; ldc = 2048; bm = t3 & 3; bn = t3 >> 2;
    }
    f32x4 acc[4][4];
    gemm_core<false>(A, B, K, lda, ldb, bm * 128, bn * 128, lA, lB, acc);
    const int lane = threadIdx.x & 63, wave = threadIdx.x >> 6;
    const int wm = wave & 1, wn = wave >> 1;
    const int rbase = bm * 128 + wm * 64 + ((lane >> 4) << 2);
    const int cbase = bn * 128 + wn * 64 + (lane & 15);
#pragma unroll
    for (int mt = 0; mt < 4; ++mt)
#pragma unroll
        for (int nt = 0; nt < 4; ++nt)
#pragma unroll
            for (int r = 0; r < 4; ++r)
                C[(size_t)(rbase + mt * 16 + r) * ldc + cbase + nt * 16] = acc[mt][nt][r];
}

// post-W1 GEMM: U_partial[ks] = Xpost(512x2048 slice) @ W1h^T, split-K x4 (K=512 each).
// 128 blocks = 4ks x (4m x 8n). f32 partials; activation deferred to head_post_k.
__global__ __launch_bounds__(256, 2) void postw1_k(const short* Xpost, const short* W1h,
                                                   float* Uacc) {
    __shared__ short lA[128 * 64];
    __shared__ short lB[128 * 64];
    const int bid = blockIdx.x;
    const int ks = bid >> 5, t2 = bid & 31, bm = t2 & 3, bn = t2 >> 2;
    const short* A = Xpost + ks * 512;
    const short* B = W1h + ks * 512;
    f32x4 acc[4][4];
    gemm_core<false>(A, B, 512, 2048, 2048, bm * 128, bn * 128, lA, lB, acc);
    float* C = Uacc + (size_t)ks * 512 * 1024;
    const int lane = threadIdx.x & 63, wave = threadIdx.x >> 6;
    const int wm = wave & 1, wn = wave >> 1;
    const int rbase = bm * 128 + wm * 64 + ((lane >> 4) << 2);
    const int cbase = bn * 128 + wn * 64 + (lane & 15);
#pragma unroll
    for (int mt = 0; mt < 4; ++mt)
#pragma unroll
        for (int nt = 0; nt < 4; ++nt)
#pragma unroll
            for (int r = 0; r < 4; ++r)
                C[(size_t)(rbase + mt * 16 + r) * 1024 + cbase + nt * 16] = acc[mt][nt][r];
}

// ---------------------------------------------------------------------------
// Weight transpose/pack: dst(N-major bf16)[n*dld + k] = src(f32)[k*sld + n]
// ---------------------------------------------------------------------------
struct TJobs {
    const float* src[9]; short* dst[9];
    int K[9], N[9], sld[9], dld[9], pre[10];
};
__global__ void transpose_pack(TJobs tj) {
    __shared__ float tile[64][65];
    int bid = blockIdx.x;
    int j = 0;
    while (bid >= tj.pre[j + 1]) ++j;
    const int rel = bid - tj.pre[j];
    const int ktiles = tj.K[j] >> 6;
    const int tk = rel % ktiles, tn = rel / ktiles;
    const float* src = tj.src[j];
    const int sld = tj.sld[j];
    const int tid = threadIdx.x;
#pragma unroll
    for (int i = 0; i < 16; ++i) {
        int idx = i * 256 + tid;
        int r = idx >> 6, c = idx & 63;
        tile[r][c] = src[(size_t)(tk * 64 + r) * sld + tn * 64 + c];
    }
    __syncthreads();
    short* dst = tj.dst[j];
    const int dld = tj.dld[j];
#pragma unroll
    for (int i = 0; i < 16; ++i) {
        int idx = i * 256 + tid;
        int r = idx >> 6, c = idx & 63;
        dst[(size_t)(tn * 64 + r) * dld + tk * 64 + c] = f2b(tile[c][r]);
    }
}

__global__ void init_state_k(const float* in_state, float* h_state, float* z_state) {
    int idx = blockIdx.x * 256 + threadIdx.x;   // 512*2080
    int b = idx / 2080, c = idx % 2080;
    float v = in_state[idx];
    if (c < 2048) h_state[b * 2048 + c] = v;
    else          z_state[b * 32 + (c - 2048)] = v;
}

// Bootstrap for t=0 only: reset + za = elu([z|a] @ za_W + za_b) (bf16 out), and
// reset-applied h (bf16 + f32).
__global__ void za_hreset_k(const float* action_t, const int* reset_t,
                            const float* za_W, const float* za_b,
                            const float* z_state, float* h_state, short* X_rz) {
    int idx = blockIdx.x * 256 + threadIdx.x;
    if (idx < 512 * 1024) {
        int b = idx >> 10, n = idx & 1023;
        bool r = reset_t[b] != 0;
        float sum = za_b[n];
        if (!r) {
#pragma unroll 8
            for (int k = 0; k < 32; ++k) sum += z_state[b * 32 + k] * za_W[k * 1024 + n];
        }
        const float* a = action_t + b * 7;
#pragma unroll
        for (int k = 0; k < 7; ++k) sum += a[k] * za_W[(32 + k) * 1024 + n];
        X_rz[b * 3072 + n] = f2b(eluf_(sum));
    } else {
        int i2 = idx - 512 * 1024;
        int b = i2 >> 11, c = i2 & 2047;
        bool r = reset_t[b] != 0;
        float h = r ? 0.f : h_state[b * 2048 + c];
        h_state[b * 2048 + c] = h;
        X_rz[b * 3072 + 1024 + c] = f2b(h);
    }
}

// GRU gates -> h_new. Reads split-K partials (Grz x2, Ghn x2). float4 vectorized.
__global__ void gate_k(const float* Grz, const float* Gin, const float* Ghn,
                       const float* bi, const float* bh, float* h_state,
                       short* Xpost, float* states_t) {
    const int idx = blockIdx.x * 256 + threadIdx.x;   // 512*512 (x4 cols)
    const int b = idx >> 9, j = (idx & 511) << 2;
    const float* g0 = Grz + (size_t)b * 4096 + j;
    const float* g1 = Grz + (size_t)512 * 4096 + (size_t)b * 4096 + j;
    const float4 r0 = *(const float4*)g0;
    const float4 r1 = *(const float4*)g1;
    const float4 z0 = *(const float4*)(g0 + 2048);
    const float4 z1 = *(const float4*)(g1 + 2048);
    const float4 bir = *(const float4*)(bi + j);
    const float4 bhr = *(const float4*)(bh + j);
    const float4 biz = *(const float4*)(bi + 2048 + j);
    const float4 bhz = *(const float4*)(bh + 2048 + j);
    const float4 gi  = *(const float4*)(Gin + (size_t)b * 2048 + j);
    const float4 h0  = *(const float4*)(Ghn + (size_t)b * 2048 + j);
    const float4 h1  = *(const float4*)(Ghn + (size_t)512 * 2048 + (size_t)b * 2048 + j);
    const float4 bin = *(const float4*)(bi + 4096 + j);
    const float4 bhn = *(const float4*)(bh + 4096 + j);
    const float4 h   = *(const float4*)(h_state + (size_t)b * 2048 + j);

    float4 hn; short4v xb;
    {
        float rg = sigmoidf_(r0.x + r1.x + bir.x + bhr.x);
        float zg = sigmoidf_(z0.x + z1.x + biz.x + bhz.x);
        float nv = tanhf(gi.x + bin.x + rg * (h0.x + h1.x + bhn.x));
        hn.x = (1.f - zg) * nv + zg * h.x; xb.x = f2b(hn.x);
    }
    {
        float rg = sigmoidf_(r0.y + r1.y + bir.y + bhr.y);
        float zg = sigmoidf_(z0.y + z1.y + biz.y + bhz.y);
        float nv = tanhf(gi.y + bin.y + rg * (h0.y + h1.y + bhn.y));
        hn.y = (1.f - zg) * nv + zg * h.y; xb.y = f2b(hn.y);
    }
    {
        float rg = sigmoidf_(r0.z + r1.z + bir.z + bhr.z);
        float zg = sigmoidf_(z0.z + z1.z + biz.z + bhz.z);
        float nv = tanhf(gi.z + bin.z + rg * (h0.z + h1.z + bhn.z));
        hn.z = (1.f - zg) * nv + zg * h.z; xb.z = f2b(hn.z);
    }
    {
        float rg = sigmoidf_(r0.w + r1.w + bir.w + bhr.w);
        float zg = sigmoidf_(z0.w + z1.w + biz.w + bhz.w);
        float nv = tanhf(gi.w + bin.w + rg * (h0.w + h1.w + bhn.w));
        hn.w = (1.f - zg) * nv + zg * h.w; xb.w = f2b(hn.w);
    }
    *(float4*)(h_state + (size_t)b * 2048 + j) = hn;
    *(float4*)(states_t + (size_t)b * 2080 + j) = hn;
    *(short4v*)(Xpost + (size_t)b * 2048 + j) = xb;
}

// Fused post head + next-step producer:
//  u = elu(sum_ks Uacc + b1 + epart); [mean|std] = u @ W2^T + b2 (softplus+0.1 on std);
//  sample = mean + std*eps -> posts/states; then builds X_rz for step t+1
//  (za = elu([masked z|a] @ za_W + b), h-part = reset-masked h) when build_next.
__global__ __launch_bounds__(256) void head_post_k(
    const float* Uacc, const float* post_b1, const short* epart_t,
    const short* W2, const float* b2, float* posts_t, const float* noise_t,
    float* states_t,
    const float* action_n, const int* reset_n, const float* za_W, const float* za_b,
    float* h_state, short* X_rz, int build_next) {
    __shared__ short urow[1024];
    __shared__ float part[256];
    __shared__ float tot[64];
    __shared__ float smp[32];
    const int b = blockIdx.x, tid = threadIdx.x;
    {
        const int c = tid * 4;
        const size_t off = (size_t)b * 1024 + c;
        const float4 s0 = *(const float4*)(Uacc + off);
        const float4 s1 = *(const float4*)(Uacc + 524288 + off);
        const float4 s2 = *(const float4*)(Uacc + 2 * 524288 + off);
        const float4 s3 = *(const float4*)(Uacc + 3 * 524288 + off);
        const float4 bb = *(const float4*)(post_b1 + c);
        const short4v e = *(const short4v*)(epart_t + off);
        short4v u;
        u.x = f2b(eluf_(s0.x + s1.x + s2.x + s3.x + bb.x + b2f(e.x)));
        u.y = f2b(eluf_(s0.y + s1.y + s2.y + s3.y + bb.y + b2f(e.y)));
        u.z = f2b(eluf_(s0.z + s1.z + s2.z + s3.z + bb.z + b2f(e.z)));
        u.w = f2b(eluf_(s0.w + s1.w + s2.w + s3.w + bb.w + b2f(e.w)));
        *(short4v*)&urow[c] = u;
    }
    __syncthreads();
    const int n = tid & 63, s = tid >> 6;
    {
        const short* w  = W2 + n * 1024 + s * 256;
        const short* ur = urow + s * 256;
        float sum = 0.f;
#pragma unroll 4
        for (int k = 0; k < 256; k += 8) {
            short8 wv = *(const short8*)(w + k);
            short8 uv = *(const short8*)(ur + k);
#pragma unroll
            for (int j = 0; j < 8; ++j) sum = fmaf(b2f(uv[j]), b2f(wv[j]), sum);
        }
        part[tid] = sum;
    }
    __syncthreads();
    if (tid < 64) tot[tid] = part[tid] + part[tid + 64] + part[tid + 128] + part[tid + 192] + b2[tid];
    __syncthreads();
    if (tid < 32) {
        float mean = tot[tid];
        float stdv = softplusf_(tot[tid + 32]) + 0.1f;
        posts_t[(size_t)b * 64 + tid] = mean;
        posts_t[(size_t)b * 64 + 32 + tid] = stdv;
        float sp = mean + stdv * noise_t[b * 32 + tid];
        states_t[(size_t)b * 2080 + 2048 + tid] = sp;
        smp[tid] = sp;
    }
    if (!build_next) return;
    __syncthreads();
    const bool rst = reset_n[b] != 0;
    {   // za part of X_rz[t+1]
        const int nn = tid * 4;
        float4 acc = *(const float4*)(za_b + nn);
        if (!rst) {
#pragma unroll 8
            for (int k = 0; k < 32; ++k) {
                const float z = smp[k];
                const float4 w = *(const float4*)(za_W + k * 1024 + nn);
                acc.x += z * w.x; acc.y += z * w.y; acc.z += z * w.z; acc.w += z * w.w;
            }
        }
        const float* a = action_n + b * 7;
#pragma unroll
        for (int k = 0; k < 7; ++k) {
            const float av = a[k];
            const float4 w = *(const float4*)(za_W + (32 + k) * 1024 + nn);
            acc.x += av * w.x; acc.y += av * w.y; acc.z += av * w.z; acc.w += av * w.w;
        }
        short4v r;
        r.x = f2b(eluf_(acc.x)); r.y = f2b(eluf_(acc.y));
        r.z = f2b(eluf_(acc.z)); r.w = f2b(eluf_(acc.w));
        *(short4v*)&X_rz[(size_t)b * 3072 + nn] = r;
    }
    {   // h part of X_rz[t+1] (+ masked h_state write)
        const int c = tid * 8;
        float4 h0, h1;
        if (rst) {
            h0 = float4{0.f, 0.f, 0.f, 0.f}; h1 = h0;
            *(float4*)(h_state + (size_t)b * 2048 + c) = h0;
            *(float4*)(h_state + (size_t)b * 2048 + c + 4) = h1;
        } else {
            h0 = *(const float4*)(h_state + (size_t)b * 2048 + c);
            h1 = *(const float4*)(h_state + (size_t)b * 2048 + c + 4);
        }
        short8 r;
        r[0] = f2b(h0.x); r[1] = f2b(h0.y); r[2] = f2b(h0.z); r[3] = f2b(h0.w);
        r[4] = f2b(h1.x); r[5] = f2b(h1.y); r[6] = f2b(h1.z); r[7] = f2b(h1.w);
        *(short8*)&X_rz[(size_t)b * 3072 + 1024 + c] = r;
    }
}

// Head for deferred priors: (rows x 1024) bf16 @ W2^T(64x1024) + b2 -> mean/std
__global__ void head_k(const short* U, const short* W2, const float* b2, float* out) {
    __shared__ short urow[1024];
    __shared__ float part[256];
    __shared__ float tot[64];
    const int b = blockIdx.x, tid = threadIdx.x;
    *(short4v*)&urow[tid * 4] = *(const short4v*)&U[(size_t)b * 1024 + tid * 4];
    __syncthreads();
    const int n = tid & 63, s = tid >> 6;
    const short* w  = W2 + n * 1024 + s * 256;
    const short* ur = urow + s * 256;
    float sum = 0.f;
#pragma unroll 4
    for (int k = 0; k < 256; k += 8) {
        short8 wv = *(const short8*)(w + k);
        short8 uv = *(const short8*)(ur + k);
#pragma unroll
        for (int j = 0; j < 8; ++j) sum = fmaf(b2f(uv[j]), b2f(wv[j]), sum);
    }
    part[tid] = sum;
    __syncthreads();
    if (tid < 64) tot[tid] = part[tid] + part[tid + 64] + part[tid + 128] + part[tid + 192] + b2[tid];
    __syncthreads();
    if (tid < 32) {
        out[(size_t)b * 64 + tid] = tot[tid];
        out[(size_t)b * 64 + 32 + tid] = softplusf_(tot[tid + 32]) + 0.1f;
    }
}

// ---------------------------------------------------------------------------
// ws layout (bytes)
// ---------------------------------------------------------------------------
constexpr size_t OFF_WRZ   = 0;                          // 4096x3072 bf16
constexpr size_t OFF_WIN   = OFF_WRZ + 25165824;         // 2048x1024 bf16
constexpr size_t OFF_WHN   = OFF_WIN + 4194304;          // 2048x2048 bf16
constexpr size_t OFF_W1H   = OFF_WHN + 8388608;          // 1024x2048 bf16
constexpr size_t OFF_W1E   = OFF_W1H + 4194304;          // 1024x1536 bf16
constexpr size_t OFF_PW1   = OFF_W1E + 3145728;          // 1024x2048 bf16
constexpr size_t OFF_W2P   = OFF_PW1 + 4194304;          // 64x1024 bf16
constexpr size_t OFF_W2R   = OFF_W2P + 131072;           // 64x1024 bf16
constexpr size_t OFF_EPART = OFF_W2R + 131072;           // 32768x1024 bf16
constexpr size_t OFF_XRZ   = OFF_EPART + 67108864;       // 512x3072 bf16
constexpr size_t OFF_XPOST = OFF_XRZ + 3145728;          // 512x2048 bf16
constexpr size_t OFF_GRZ   = OFF_XPOST + 2097152;        // 2x 512x4096 f32 (Uacc/Upri alias)
constexpr size_t OFF_GIN   = OFF_GRZ + 16777216;         // 512x2048 f32
constexpr size_t OFF_GHN   = OFF_GIN + 4194304;          // 2x 512x2048 f32
constexpr size_t OFF_H     = OFF_GHN + 8388608;          // 512x2048 f32
constexpr size_t OFF_Z     = OFF_H + 4194304;            // 512x32 f32
// total = OFF_Z + 65536 = 155516928 (~148.3 MiB)

extern "C" void kernel_launch(void* const* d_in, const int* in_sizes, int n_in,
                              void* d_out, int out_size, void* d_ws, size_t ws_size,
                              hipStream_t stream) {
    const float* embed    = (const float*)d_in[0];
    const float* action   = (const float*)d_in[1];
    const float* noise    = (const float*)d_in[2];
    const float* in_state = (const float*)d_in[3];
    const float* za_W     = (const float*)d_in[4];
    const float* za_b     = (const float*)d_in[5];
    const float* gru_Wi   = (const float*)d_in[6];
    const float* gru_Wh   = (const float*)d_in[7];
    const float* gru_bi   = (const float*)d_in[8];
    const float* gru_bh   = (const float*)d_in[9];
    const float* prior_W1 = (const float*)d_in[10];
    const float* prior_b1 = (const float*)d_in[11];
    const float* prior_W2 = (const float*)d_in[12];
    const float* prior_b2 = (const float*)d_in[13];
    const float* post_W1  = (const float*)d_in[14];
    const float* post_b1  = (const float*)d_in[15];
    const float* post_W2  = (const float*)d_in[16];
    const float* post_b2  = (const float*)d_in[17];
    const int*   reset    = (const int*)d_in[18];   // bool marshalled as int32

    char* ws = (char*)d_ws;
    short* W_rz  = (short*)(ws + OFF_WRZ);
    short* Wi_n  = (short*)(ws + OFF_WIN);
    short* Wh_n  = (short*)(ws + OFF_WHN);
    short* W1h   = (short*)(ws + OFF_W1H);
    short* W1e   = (short*)(ws + OFF_W1E);
    short* PW1   = (short*)(ws + OFF_PW1);
    short* W2p   = (short*)(ws + OFF_W2P);
    short* W2r   = (short*)(ws + OFF_W2R);
    short* epart = (short*)(ws + OFF_EPART);
    short* X_rz  = (short*)(ws + OFF_XRZ);
    short* Xpost = (short*)(ws + OFF_XPOST);
    float* Grz   = (float*)(ws + OFF_GRZ);
    float* Gin   = (float*)(ws + OFF_GIN);
    float* Ghn   = (float*)(ws + OFF_GHN);
    float* h_st  = (float*)(ws + OFF_H);
    float* z_st  = (float*)(ws + OFF_Z);
    float* Uacc  = (float*)(ws + OFF_GRZ);   // aliases Grz (dead by the time postw1 runs)
    short* Upri  = (short*)(ws + OFF_GRZ);   // aliases Grz (phase 5 only)

    float* priors = (float*)d_out;
    float* posts  = priors + (size_t)T_STEPS * BATCH * 64;
    float* states = posts + (size_t)T_STEPS * BATCH * 64;

    dim3 blk(256);

    // 1. transpose/pack weights to bf16 N-major
    TJobs tj;
    const float* srcs[9] = { gru_Wi, gru_Wh, gru_Wi + 4096, gru_Wh + 4096,
                             post_W1, post_W1 + (size_t)2048 * 1024, prior_W1,
                             post_W2, prior_W2 };
    short* dsts[9] = { W_rz, W_rz + 1024, Wi_n, Wh_n, W1h, W1e, PW1, W2p, W2r };
    int Ks[9]   = { 1024, 2048, 1024, 2048, 2048, 1536, 2048, 1024, 1024 };
    int Ns[9]   = { 4096, 4096, 2048, 2048, 1024, 1024, 1024, 64, 64 };
    int slds[9] = { 6144, 6144, 6144, 6144, 1024, 1024, 1024, 64, 64 };
    int dlds[9] = { 3072, 3072, 1024, 2048, 2048, 1536, 2048, 1024, 1024 };
    tj.pre[0] = 0;
    for (int j = 0; j < 9; ++j) {
        tj.src[j] = srcs[j]; tj.dst[j] = dsts[j];
        tj.K[j] = Ks[j]; tj.N[j] = Ns[j]; tj.sld[j] = slds[j]; tj.dld[j] = dlds[j];
        tj.pre[j + 1] = tj.pre[j] + (Ks[j] >> 6) * (Ns[j] >> 6);
    }
    transpose_pack<<<tj.pre[9], blk, 0, stream>>>(tj);

    // 2. init recurrent state
    init_state_k<<<(512 * 2080) / 256, blk, 0, stream>>>(in_state, h_st, z_st);

    // 3. precompute e_part = embed @ post_W1[D:,:]  (bf16 out)
    {
        Epi ep{}; ep.Cb = epart; ep.ldcb = 1024;
        gemm_k<true><<<256 * 8, blk, 0, stream>>>(embed, W1e, 1536, 1536, 1536, 256, ep);
    }

    // 4. bootstrap X_rz for t=0
    za_hreset_k<<<6144, blk, 0, stream>>>(action, reset, za_W, za_b, z_st, h_st, X_rz);

    // 5. sequential scan: gates -> gate -> postw1 -> head (head builds X_rz for t+1)
    for (int t = 0; t < T_STEPS; ++t) {
        gates_k<<<448, blk, 0, stream>>>(X_rz, W_rz, Wi_n, Wh_n, Grz, Gin, Ghn);
        gate_k<<<1024, blk, 0, stream>>>(Grz, Gin, Ghn, gru_bi, gru_bh, h_st, Xpost,
                                         states + (size_t)t * 512 * 2080);
        postw1_k<<<128, blk, 0, stream>>>(Xpost, W1h, Uacc);
        head_post_k<<<512, blk, 0, stream>>>(
            Uacc, post_b1, epart + (size_t)t * 512 * 1024, W2p, post_b2,
            posts + (size_t)t * 512 * 64, noise + (size_t)t * 512 * 32,
            states + (size_t)t * 512 * 2080,
            action + (size_t)(t + 1) * 512 * 7, reset + (size_t)(t + 1) * 512,
            za_W, za_b, h_st, X_rz, t < T_STEPS - 1);
    }

    // 6. deferred priors, 4 chunks of 16 timesteps
    for (int c = 0; c < 4; ++c) {
        Epi ep2{}; ep2.bias = prior_b1; ep2.elu = 1; ep2.Cb = Upri; ep2.ldcb = 1024;
        gemm_k<true><<<64 * 8, blk, 0, stream>>>(states + (size_t)c * 16 * 512 * 2080, PW1,
                                                 2048, 2080, 2048, 64, ep2);
        head_k<<<8192, blk, 0, stream>>>(Upri, W2r, prior_b2, priors + (size_t)c * 8192 * 64);
    }
    (void)ws_size; (void)out_size; (void)n_in; (void)in_sizes;
}